// Round 11
// baseline (205.528 us; speedup 1.0000x reference)
//
#include <hip/hip_runtime.h>

// Conv2d: N=32, Cin=128, H=W=56, Cout=256, K=3, s=1, p=1. fp32 in/out, bf16 MFMA.
// R9: 128oc x 256pix block tile, 4 waves of 64x128 (intensity 32->42.7 F/B),
//     3-deep counted-vmcnt pipeline (kept from R5), BK=32, 36 steps.

typedef __attribute__((ext_vector_type(8))) short short8;   // 8 bf16
typedef __attribute__((ext_vector_type(4))) float f32x4;
typedef unsigned short ushort_t;

#define HWSZ 56
#define HW2 3136
#define INC 128
#define OUTC 256
#define PADW 58
#define XT_ELEMS 13778944          // 32*58*58*128

__device__ __forceinline__ ushort_t f2b(float f) {
    union { float f; unsigned u; } v; v.f = f;
    unsigned r = v.u + 0x7fffu + ((v.u >> 16) & 1u);   // RNE
    return (ushort_t)(r >> 16);
}

__device__ __forceinline__ void glds16(const void* g, void* l) {
    __builtin_amdgcn_global_load_lds(
        (const __attribute__((address_space(1))) unsigned*)g,
        (__attribute__((address_space(3))) unsigned*)l, 16, 0, 0);
}

// ---- Pass 0: zero only the halo ring of xt ----
__global__ __launch_bounds__(256) void halo_zero(ushort_t* __restrict__ xt) {
    const int tid = blockIdx.x * 256 + threadIdx.x;   // 456 blocks
    const int g = tid & 15;
    const int p = tid >> 4;
    const int n = p / 228;
    const int bp = p - n * 228;
    int h, wv;
    if (bp < 58)       { h = 0;        wv = bp; }
    else if (bp < 116) { h = 57;       wv = bp - 58; }
    else if (bp < 172) { h = bp - 115; wv = 0; }
    else               { h = bp - 171; wv = 57; }
    const short8 z = {0,0,0,0,0,0,0,0};
    *reinterpret_cast<short8*>(xt + (((size_t)n * PADW + h) * PADW + wv) * INC + g * 8) = z;
}

// ---- Pass 1: x[n][c][h][w] f32 -> xt[n][h+1][w+1][c] bf16 ----
__global__ __launch_bounds__(256) void xt_kernel(const float* __restrict__ x,
                                                 ushort_t* __restrict__ xt) {
    __shared__ float tile[128][65];
    const int b = blockIdx.x;          // 32*49
    const int n = b / 49;
    const int hw0 = (b - n * 49) * 64;
    const int t = threadIdx.x;

    const float* xp = x + (size_t)n * (INC * HW2) + hw0;
    const int c_base = t >> 4;
    const int hwo = (t & 15) * 4;
#pragma unroll
    for (int j = 0; j < 8; ++j) {
        const int c = j * 16 + c_base;
        const f32x4 v = *reinterpret_cast<const f32x4*>(xp + c * HW2 + hwo);
        tile[c][hwo + 0] = v[0];
        tile[c][hwo + 1] = v[1];
        tile[c][hwo + 2] = v[2];
        tile[c][hwo + 3] = v[3];
    }
    __syncthreads();
    const int hw = t >> 2;
    const int q = t & 3;
    const int P = hw0 + hw;
    const int oh = P / HWSZ;
    const int ow = P - oh * HWSZ;
    ushort_t* dst = xt + (((size_t)n * PADW + oh + 1) * PADW + (ow + 1)) * INC;
#pragma unroll
    for (int g = 0; g < 4; ++g) {
        short8 v;
#pragma unroll
        for (int e = 0; e < 8; ++e) v[e] = (short)f2b(tile[g * 32 + q * 8 + e][hw]);
        *reinterpret_cast<short8*>(dst + g * 32 + q * 8) = v;
    }
}

// ---- Pass 2: w -> wt2 panels (unchanged format: [oc_tile][step][512 slots][8]) ----
__global__ __launch_bounds__(256) void wt_kernel(const float* __restrict__ w,
                                                 ushort_t* __restrict__ wt2) {
    const int tid = blockIdx.x * 256 + threadIdx.x;   // 144 blocks
    const int panel = tid >> 9;
    const int s = tid & 511;
    const int oc_tile = panel / 36;
    const int rem = panel - oc_tile * 36;
    const int pos = rem >> 2;
    const int icc = rem & 3;
    const int row = s >> 2;
    const int fq = (s & 3) ^ ((row >> 1) & 3);
    const int oc = oc_tile * 128 + row;
    const int ic0 = icc * 32 + fq * 8;
    short8 v;
#pragma unroll
    for (int e = 0; e < 8; ++e) v[e] = (short)f2b(w[(oc * 128 + ic0 + e) * 9 + pos]);
    *reinterpret_cast<short8*>(wt2 + (size_t)tid * 8) = v;
}

// ---- Pass 3: implicit GEMM, 128x256 tile, BK=32, 3-deep counted-vmcnt pipeline ----
__global__ __launch_bounds__(256, 2) void conv_main(const ushort_t* __restrict__ xt,
                                                    const ushort_t* __restrict__ wt2,
                                                    const float* __restrict__ bias,
                                                    float* __restrict__ out) {
    __shared__ ushort_t lds[3][12288];   // [buf][A:4096 | B:8192 elems] = 72 KB

    const int bid = blockIdx.x;
    const int work = (bid & 7) * 98 + (bid >> 3);   // XCD-bijective (784 = 8*98)
    const int oc_tile = work & 1;
    const int P0 = (work >> 1) * 256;

    const int t = threadIdx.x;
    const int w = t >> 6;
    const int l = t & 63;
    const int fr = l & 15;
    const int fq = l >> 4;
    const int wr = w >> 1;     // oc half   (64 rows)
    const int wc = w & 1;      // pix half  (128 cols)

    const ushort_t* Abase = wt2 + (size_t)oc_tile * (36 * 4096) + t * 8;

    // B staging: 16 KB/step = 16 wave-writes of 1 KB; wave w does k=0..3 at
    // row-blocks (w+4k)*16. Lane l -> row +(l>>2), stored chunk (l&3);
    // source chunk = (l&3)^((row>>1)&3) = (l&3)^((l>>3)&3)  (swz).
    const int swz = ((l & 3) ^ ((l >> 3) & 3)) * 8;
    const ushort_t* xr0;
    const ushort_t* xr1;
    const ushort_t* xr2;
    const ushort_t* xr3;
    {
        const ushort_t* tmp[4];
#pragma unroll
        for (int k = 0; k < 4; ++k) {
            const int row = (w + 4 * k) * 16 + (l >> 2);
            const int P = P0 + row;
            const int n = P / HW2; const int hw = P - n * HW2;
            const int oh = hw / HWSZ; const int ow = hw - oh * HWSZ;
            tmp[k] = xt + (((size_t)n * PADW + oh) * PADW + ow) * INC + swz;
        }
        xr0 = tmp[0]; xr1 = tmp[1]; xr2 = tmp[2]; xr3 = tmp[3];
    }

    // fragment read offset: row=..+fr, chunk fq^((fr>>1)&3) -> 2-way max (free)
    const int frag_off = fr * 32 + ((fq ^ ((fr >> 1) & 3)) * 8);

    f32x4 acc[4][8];
#pragma unroll
    for (int i = 0; i < 4; ++i)
#pragma unroll
        for (int j = 0; j < 8; ++j) { f32x4 z = {0.f,0.f,0.f,0.f}; acc[i][j] = z; }

    auto stage = [&](int s1, int bsel) {
        const int pos = s1 >> 2;
        const int icc = s1 & 3;
        const int kh = pos / 3;
        const int kw = pos - kh * 3;
        const int koff = (kh * PADW + kw) * INC + icc * 32;
        const ushort_t* Ab = Abase + s1 * 4096;
        glds16(Ab,          &lds[bsel][w * 512]);
        glds16(Ab + 2048,   &lds[bsel][(w + 4) * 512]);
        glds16(xr0 + koff,  &lds[bsel][4096 + (w +  0) * 512]);
        glds16(xr1 + koff,  &lds[bsel][4096 + (w +  4) * 512]);
        glds16(xr2 + koff,  &lds[bsel][4096 + (w +  8) * 512]);
        glds16(xr3 + koff,  &lds[bsel][4096 + (w + 12) * 512]);
    };

    auto compute = [&](int bsel) {
        const ushort_t* A = &lds[bsel][0];
        const ushort_t* B = &lds[bsel][4096];
        short8 af[4], bf[4];
#pragma unroll
        for (int mi = 0; mi < 4; ++mi)
            af[mi] = *reinterpret_cast<const short8*>(A + wr * 2048 + mi * 512 + frag_off);
        // first pix half-group (ni 0..3)
#pragma unroll
        for (int ni = 0; ni < 4; ++ni)
            bf[ni] = *reinterpret_cast<const short8*>(B + wc * 4096 + ni * 512 + frag_off);
        __builtin_amdgcn_s_setprio(1);
#pragma unroll
        for (int mi = 0; mi < 4; ++mi)
#pragma unroll
            for (int ni = 0; ni < 4; ++ni)
                acc[mi][ni] = __builtin_amdgcn_mfma_f32_16x16x32_bf16(af[mi], bf[ni],
                                                                      acc[mi][ni], 0, 0, 0);
        __builtin_amdgcn_s_setprio(0);
        // second pix half-group (ni 4..7)
#pragma unroll
        for (int ni = 0; ni < 4; ++ni)
            bf[ni] = *reinterpret_cast<const short8*>(B + wc * 4096 + (ni + 4) * 512 + frag_off);
        __builtin_amdgcn_s_setprio(1);
#pragma unroll
        for (int mi = 0; mi < 4; ++mi)
#pragma unroll
            for (int ni = 0; ni < 4; ++ni)
                acc[mi][ni + 4] = __builtin_amdgcn_mfma_f32_16x16x32_bf16(af[mi], bf[ni],
                                                                          acc[mi][ni + 4], 0, 0, 0);
        __builtin_amdgcn_s_setprio(0);
    };

    // prologue: 2 buffers in flight (12 outstanding loads)
    stage(0, 0);
    stage(1, 1);

    int bc = 0, bn = 2;
    for (int s = 0; s < 35; ++s) {
        // wait own 6 (buf bc) -> leaves next buf's 6 in flight across barrier
        asm volatile("s_waitcnt vmcnt(6)\n\ts_barrier" ::: "memory");
        if (s < 34) stage(s + 2, bn);
        compute(bc);
        bc = (bc == 2) ? 0 : bc + 1;
        bn = (bn == 2) ? 0 : bn + 1;
    }
    asm volatile("s_waitcnt vmcnt(0)\n\ts_barrier" ::: "memory");
    compute(bc);

    // epilogue: D row(oc)=fq*4+r, col(pix)=fr
    const int oc0 = oc_tile * 128;
    float bmr[4][4];
#pragma unroll
    for (int mi = 0; mi < 4; ++mi)
#pragma unroll
        for (int r = 0; r < 4; ++r)
            bmr[mi][r] = bias[oc0 + wr * 64 + mi * 16 + fq * 4 + r];

#pragma unroll
    for (int ni = 0; ni < 8; ++ni) {
        const int Pp = P0 + wc * 128 + ni * 16 + fr;
        const int nn = Pp / HW2;
        const int hwp = Pp - nn * HW2;
        float* op = out + (size_t)nn * (OUTC * HW2) + hwp;
#pragma unroll
        for (int mi = 0; mi < 4; ++mi)
#pragma unroll
            for (int r = 0; r < 4; ++r) {
                const int oc = oc0 + wr * 64 + mi * 16 + fq * 4 + r;
                op[oc * HW2] = acc[mi][ni][r] + bmr[mi][r];
            }
    }
}

extern "C" void kernel_launch(void* const* d_in, const int* in_sizes, int n_in,
                              void* d_out, int out_size, void* d_ws, size_t ws_size,
                              hipStream_t stream) {
    const float* x = (const float*)d_in[0];
    const float* w = (const float*)d_in[1];
    const float* bias = (const float*)d_in[2];
    float* out = (float*)d_out;

    ushort_t* xt = (ushort_t*)d_ws;            // 27,557,888 B (halo-padded)
    ushort_t* wt2 = xt + XT_ELEMS;             // 589,824 B

    halo_zero<<<456, 256, 0, stream>>>(xt);
    xt_kernel<<<1568, 256, 0, stream>>>(x, xt);
    wt_kernel<<<144, 256, 0, stream>>>(w, wt2);
    conv_main<<<784, 256, 0, stream>>>(xt, wt2, bias, out);
}

// Round 14
// 202.720 us; speedup vs baseline: 1.0139x; 1.0139x over previous
//
#include <hip/hip_runtime.h>

// Conv2d: N=32, Cin=128, H=W=56, Cout=256, K=3, s=1, p=1. fp32 in/out, bf16 MFMA.
// R13: R8 geometry (128x128, 3 blocks/CU) + race-free two-barrier read-early
//      schedule: stage(s+2) + read_frags(s) -> B1 -> MFMA -> vmcnt(4) -> B2.
//      (R12's read-ahead raced: ds_read before the barrier that collectivizes
//       other waves' glds16. Fixed per m201's two-barrier phase structure.)

typedef __attribute__((ext_vector_type(8))) short short8;   // 8 bf16
typedef __attribute__((ext_vector_type(4))) float f32x4;
typedef unsigned short ushort_t;

#define HWSZ 56
#define HW2 3136
#define INC 128
#define OUTC 256
#define PADW 58
#define XT_ELEMS 13778944          // 32*58*58*128

__device__ __forceinline__ ushort_t f2b(float f) {
    union { float f; unsigned u; } v; v.f = f;
    unsigned r = v.u + 0x7fffu + ((v.u >> 16) & 1u);   // RNE
    return (ushort_t)(r >> 16);
}

__device__ __forceinline__ void glds16(const void* g, void* l) {
    __builtin_amdgcn_global_load_lds(
        (const __attribute__((address_space(1))) unsigned*)g,
        (__attribute__((address_space(3))) unsigned*)l, 16, 0, 0);
}

// ---- Pass 0: zero only the halo ring of xt ----
__global__ __launch_bounds__(256) void halo_zero(ushort_t* __restrict__ xt) {
    const int tid = blockIdx.x * 256 + threadIdx.x;   // 456 blocks
    const int g = tid & 15;
    const int p = tid >> 4;
    const int n = p / 228;
    const int bp = p - n * 228;
    int h, wv;
    if (bp < 58)       { h = 0;        wv = bp; }
    else if (bp < 116) { h = 57;       wv = bp - 58; }
    else if (bp < 172) { h = bp - 115; wv = 0; }
    else               { h = bp - 171; wv = 57; }
    const short8 z = {0,0,0,0,0,0,0,0};
    *reinterpret_cast<short8*>(xt + (((size_t)n * PADW + h) * PADW + wv) * INC + g * 8) = z;
}

// ---- Pass 1: x[n][c][h][w] f32 -> xt[n][h+1][w+1][c] bf16 ----
__global__ __launch_bounds__(256) void xt_kernel(const float* __restrict__ x,
                                                 ushort_t* __restrict__ xt) {
    __shared__ float tile[128][65];
    const int b = blockIdx.x;          // 32*49
    const int n = b / 49;
    const int hw0 = (b - n * 49) * 64;
    const int t = threadIdx.x;

    const float* xp = x + (size_t)n * (INC * HW2) + hw0;
    const int c_base = t >> 4;
    const int hwo = (t & 15) * 4;
#pragma unroll
    for (int j = 0; j < 8; ++j) {
        const int c = j * 16 + c_base;
        const f32x4 v = *reinterpret_cast<const f32x4*>(xp + c * HW2 + hwo);
        tile[c][hwo + 0] = v[0];
        tile[c][hwo + 1] = v[1];
        tile[c][hwo + 2] = v[2];
        tile[c][hwo + 3] = v[3];
    }
    __syncthreads();
    const int hw = t >> 2;
    const int q = t & 3;
    const int P = hw0 + hw;
    const int oh = P / HWSZ;
    const int ow = P - oh * HWSZ;
    ushort_t* dst = xt + (((size_t)n * PADW + oh + 1) * PADW + (ow + 1)) * INC;
#pragma unroll
    for (int g = 0; g < 4; ++g) {
        short8 v;
#pragma unroll
        for (int e = 0; e < 8; ++e) v[e] = (short)f2b(tile[g * 32 + q * 8 + e][hw]);
        *reinterpret_cast<short8*>(dst + g * 32 + q * 8) = v;
    }
}

// ---- Pass 2: w -> wt2 panels ([oc_tile][step][512 slots][8], fragment order) ----
__global__ __launch_bounds__(256) void wt_kernel(const float* __restrict__ w,
                                                 ushort_t* __restrict__ wt2) {
    const int tid = blockIdx.x * 256 + threadIdx.x;   // 144 blocks
    const int panel = tid >> 9;
    const int s = tid & 511;
    const int oc_tile = panel / 36;
    const int rem = panel - oc_tile * 36;
    const int pos = rem >> 2;
    const int icc = rem & 3;
    const int row = s >> 2;
    const int fq = (s & 3) ^ ((row >> 1) & 3);
    const int oc = oc_tile * 128 + row;
    const int ic0 = icc * 32 + fq * 8;
    short8 v;
#pragma unroll
    for (int e = 0; e < 8; ++e) v[e] = (short)f2b(w[(oc * 128 + ic0 + e) * 9 + pos]);
    *reinterpret_cast<short8*>(wt2 + (size_t)tid * 8) = v;
}

// ---- Pass 3: implicit GEMM, 128x128 tile, BK=32, two-barrier read-early loop ----
__global__ __launch_bounds__(256, 3) void conv_main(const ushort_t* __restrict__ xt,
                                                    const ushort_t* __restrict__ wt2,
                                                    const float* __restrict__ bias,
                                                    float* __restrict__ out) {
    __shared__ ushort_t lds[3][2][4096];   // 48 KB -> 3 blocks/CU

    const int bid = blockIdx.x;
    const int work = (bid & 7) * 196 + (bid >> 3);   // XCD-bijective (1568 = 8*196)
    const int oc_tile = work & 1;
    const int P0 = (work >> 1) * 128;

    const int t = threadIdx.x;
    const int w = t >> 6;
    const int l = t & 63;
    const int fr = l & 15;
    const int fq = l >> 4;
    const int wr = w >> 1;
    const int wc = w & 1;

    const ushort_t* Abase = wt2 + (size_t)oc_tile * (36 * 4096) + t * 8;

    const int pa = w * 16 + (l >> 2);
    const int Pa = P0 + pa;
    const int na = Pa / HW2; const int hwa = Pa - na * HW2;
    const int oha = hwa / HWSZ; const int owa = hwa - oha * HWSZ;
    const int Pb = Pa + 64;
    const int nb = Pb / HW2; const int hwb = Pb - nb * HW2;
    const int ohb = hwb / HWSZ; const int owb = hwb - ohb * HWSZ;
    const ushort_t* xra = xt + (((size_t)na * PADW + oha) * PADW + owa) * INC;
    const ushort_t* xrb = xt + (((size_t)nb * PADW + ohb) * PADW + owb) * INC;
    const int swz = ((l & 3) ^ ((l >> 3) & 3)) * 8;

    const int frag_off = fr * 32 + ((fq ^ ((fr >> 1) & 3)) * 8);

    f32x4 acc[4][4];
#pragma unroll
    for (int i = 0; i < 4; ++i)
#pragma unroll
        for (int j = 0; j < 4; ++j) { f32x4 z = {0.f,0.f,0.f,0.f}; acc[i][j] = z; }

    auto stage = [&](int s1, int bsel) {
        const int pos = s1 >> 2;
        const int icc = s1 & 3;
        const int kh = pos / 3;
        const int kw = pos - kh * 3;
        const int koff = (kh * PADW + kw) * INC + icc * 32;
        const ushort_t* Ab = Abase + s1 * 4096;
        glds16(Ab,               &lds[bsel][0][w * 512]);
        glds16(Ab + 2048,        &lds[bsel][0][(w + 4) * 512]);
        glds16(xra + koff + swz, &lds[bsel][1][w * 512]);
        glds16(xrb + koff + swz, &lds[bsel][1][(w + 4) * 512]);
    };

    short8 af[4], bf[4];
    auto read_frags = [&](int bsel) {
#pragma unroll
        for (int mi = 0; mi < 4; ++mi)
            af[mi] = *reinterpret_cast<const short8*>(&lds[bsel][0][wr * 2048 + mi * 512 + frag_off]);
#pragma unroll
        for (int ni = 0; ni < 4; ++ni)
            bf[ni] = *reinterpret_cast<const short8*>(&lds[bsel][1][wc * 2048 + ni * 512 + frag_off]);
    };

    // prologue: 2 buffers in flight; collectivize buf0 before any ds_read
    stage(0, 0);
    stage(1, 1);
    asm volatile("s_waitcnt vmcnt(4)" ::: "memory");   // own stage(0) landed
    __builtin_amdgcn_s_barrier();                      // all waves' stage(0) landed

    int bc = 0;
    for (int s = 0; s < 36; ++s) {
        // invariant at entry: buf[bc] collectively staged; buf[(bc+2)%3] fully
        // read by all waves (drained before B2 of iter s-1) -> stage is WAR-safe
        if (s < 34) stage(s + 2, bc == 0 ? 2 : bc - 1);    // (bc+2)%3
        read_frags(bc);                                    // issue early...
        __builtin_amdgcn_s_barrier();                      // B1: latency hides here
        __builtin_amdgcn_s_setprio(1);                     // (compiler lgkm-waits)
#pragma unroll
        for (int mi = 0; mi < 4; ++mi)
#pragma unroll
            for (int ni = 0; ni < 4; ++ni)
                acc[mi][ni] = __builtin_amdgcn_mfma_f32_16x16x32_bf16(af[mi], bf[ni],
                                                                      acc[mi][ni], 0, 0, 0);
        __builtin_amdgcn_s_setprio(0);
        if (s < 35) {
            if (s < 34) asm volatile("s_waitcnt vmcnt(4)" ::: "memory");  // own stage(s+1) landed
            else        asm volatile("s_waitcnt vmcnt(0)" ::: "memory");  // drain for last step
            __builtin_amdgcn_s_barrier();   // B2: collectivize stage(s+1); reads(s) drained
        }
        bc = (bc == 2) ? 0 : bc + 1;
    }

    // epilogue: D row(oc)=fq*4+r, col(pix)=fr
    const int oc0 = oc_tile * 128;
    float bmr[4][4];
#pragma unroll
    for (int mi = 0; mi < 4; ++mi)
#pragma unroll
        for (int r = 0; r < 4; ++r)
            bmr[mi][r] = bias[oc0 + wr * 64 + mi * 16 + fq * 4 + r];

#pragma unroll
    for (int ni = 0; ni < 4; ++ni) {
        const int Pp = P0 + wc * 64 + ni * 16 + fr;
        const int nn = Pp / HW2;
        const int hwp = Pp - nn * HW2;
        float* op = out + (size_t)nn * (OUTC * HW2) + hwp;
#pragma unroll
        for (int mi = 0; mi < 4; ++mi)
#pragma unroll
            for (int r = 0; r < 4; ++r) {
                const int oc = oc0 + wr * 64 + mi * 16 + fq * 4 + r;
                op[oc * HW2] = acc[mi][ni][r] + bmr[mi][r];
            }
    }
}

extern "C" void kernel_launch(void* const* d_in, const int* in_sizes, int n_in,
                              void* d_out, int out_size, void* d_ws, size_t ws_size,
                              hipStream_t stream) {
    const float* x = (const float*)d_in[0];
    const float* w = (const float*)d_in[1];
    const float* bias = (const float*)d_in[2];
    float* out = (float*)d_out;

    ushort_t* xt = (ushort_t*)d_ws;            // 27,557,888 B (halo-padded)
    ushort_t* wt2 = xt + XT_ELEMS;             // 589,824 B

    halo_zero<<<456, 256, 0, stream>>>(xt);
    xt_kernel<<<1568, 256, 0, stream>>>(x, xt);
    wt_kernel<<<144, 256, 0, stream>>>(w, wt2);
    conv_main<<<1568, 256, 0, stream>>>(xt, wt2, bias, out);
}